// Round 3
// baseline (582.794 us; speedup 1.0000x reference)
//
#include <hip/hip_runtime.h>
#include <math.h>

// Problem constants
#define HID   4096
#define SLOTS 8
#define HEADS 8
#define BD    512
#define HD    64
#define BB    4
#define SS    4096
#define R64   64          // HEADS*SLOTS rows; r = h*8 + n

typedef __attribute__((ext_vector_type(8))) short bf16x8;
typedef __attribute__((ext_vector_type(4))) float f32x4;

// fp32 -> bf16 bits, round-to-nearest-even (inputs finite)
__device__ __forceinline__ unsigned short f2bf(float x) {
  unsigned int u = __builtin_bit_cast(unsigned int, x);
  return (unsigned short)((u + 0x7fffu + ((u >> 16) & 1u)) >> 16);
}

// LDS tile: 64 rows x 64 bf16, row = 128 B, XOR-swizzled 16B chunks:
//   elem(row, k) lives at short-index  row*64 + (((k>>3) ^ (row&7))<<3) + (k&7)
// Frag reads (ds_read_b128) then start at bank 4*((chunk^row)&7): 2-way only.

// ---- 1: Q = ms @ Wq^T  (8x512). One wave per output element.
__global__ void q_kernel(const float* __restrict__ ms, const float* __restrict__ Wq,
                         float* __restrict__ Q) {
  int w = (blockIdx.x * blockDim.x + threadIdx.x) >> 6;
  int lane = threadIdx.x & 63;
  if (w >= SLOTS * BD) return;
  int n = w >> 9, o = w & (BD - 1);
  const float* a = ms + n * HID;
  const float* b = Wq + (size_t)o * HID;
  float acc = 0.f;
  for (int i = lane; i < HID; i += 64) acc = fmaf(a[i], b[i], acc);
  #pragma unroll
  for (int off = 32; off; off >>= 1) acc += __shfl_down(acc, off, 64);
  if (lane == 0) Q[w] = acc;
}

// ---- 2: QW[r][i] = 0.125 * sum_d Q[n][h*64+d] * Wk[h*64+d][i],  r = h*8+n  (bf16 out)
__global__ void qw_kernel(const float* __restrict__ Q, const float* __restrict__ Wk,
                          unsigned short* __restrict__ QW) {
  int idx = blockIdx.x * blockDim.x + threadIdx.x;   // 64*4096
  int r = idx >> 12, i = idx & (HID - 1);
  int h = r >> 3, n = r & 7;
  const float* q  = Q + n * BD + h * HD;
  const float* wk = Wk + (size_t)(h * HD) * HID + i;
  float acc = 0.f;
  #pragma unroll 8
  for (int d = 0; d < HD; ++d) acc = fmaf(q[d], wk[(size_t)d * HID], acc);
  QW[idx] = f2bf(acc * 0.125f);
}

// ---- 3: partial scores sp[ks][b][r][s] = sum_{k-slice} hs[b][s][k]*QW[r][k]  (bf16 MFMA)
// Also writes the converted hs tile to hs_bf16 (fused fp32->bf16 conversion pass).
// grid (64 stile, 4 ks, 4 b), 256 thr. Tile M=64(s) x N=64(r), K-slice=1024.
__global__ __launch_bounds__(256, 4) void scores_mfma(const float* __restrict__ hs,
                                                      const unsigned short* __restrict__ QW,
                                                      float* __restrict__ sp,
                                                      unsigned short* __restrict__ hsbf) {
  __shared__ unsigned short As[64 * 64];  // [s][k] swizzled
  __shared__ unsigned short Bs[64 * 64];  // [r][k] swizzled
  const int stile = blockIdx.x, ks = blockIdx.y, b = blockIdx.z;
  const int tid = threadIdx.x;
  const int wv = tid >> 6, lane = tid & 63;
  const int quad = lane >> 4, l16 = lane & 15;
  // staging map: thread -> (row 0..63, 16 contiguous k at kc); chunks 2*(tid&3), +1
  const int srow = tid >> 2, kc = (tid & 3) << 4;
  const int ch0 = (tid & 3) << 1;
  const int sw = srow & 7;
  const size_t arowoff = (size_t)(b * SS + stile * 64 + srow) * HID + ks * 1024 + kc;
  const float* hsp = hs + arowoff;
  unsigned short* hso = hsbf + arowoff;
  const unsigned short* qwp = QW + (size_t)srow * HID + ks * 1024 + kc;
  unsigned short* asw0 = &As[srow * 64 + (((ch0 + 0) ^ sw) << 3)];
  unsigned short* asw1 = &As[srow * 64 + (((ch0 + 1) ^ sw) << 3)];
  unsigned short* bsw0 = &Bs[srow * 64 + (((ch0 + 0) ^ sw) << 3)];
  unsigned short* bsw1 = &Bs[srow * 64 + (((ch0 + 1) ^ sw) << 3)];

  f32x4 acc[4] = {};
  float4 fa0 = *(const float4*)(hsp + 0);
  float4 fa1 = *(const float4*)(hsp + 4);
  float4 fa2 = *(const float4*)(hsp + 8);
  float4 fa3 = *(const float4*)(hsp + 12);
  uint4 qb0 = *(const uint4*)(qwp);
  uint4 qb1 = *(const uint4*)(qwp + 8);

  for (int c = 0; c < 16; ++c) {
    __syncthreads();
    union { unsigned short us[16]; uint4 q[2]; } u;
    float f[16] = {fa0.x, fa0.y, fa0.z, fa0.w, fa1.x, fa1.y, fa1.z, fa1.w,
                   fa2.x, fa2.y, fa2.z, fa2.w, fa3.x, fa3.y, fa3.z, fa3.w};
    #pragma unroll
    for (int j = 0; j < 16; ++j) u.us[j] = f2bf(f[j]);
    *(uint4*)asw0 = u.q[0];
    *(uint4*)asw1 = u.q[1];
    *(uint4*)bsw0 = qb0;
    *(uint4*)bsw1 = qb1;
    // fused bf16 conversion write-out (same values as LDS)
    *(uint4*)(hso + (size_t)c * 64)     = u.q[0];
    *(uint4*)(hso + (size_t)c * 64 + 8) = u.q[1];
    __syncthreads();
    if (c < 15) {
      const float* p = hsp + (size_t)(c + 1) * 64;
      fa0 = *(const float4*)(p + 0);
      fa1 = *(const float4*)(p + 4);
      fa2 = *(const float4*)(p + 8);
      fa3 = *(const float4*)(p + 12);
      const unsigned short* q = qwp + (size_t)(c + 1) * 64;
      qb0 = *(const uint4*)(q);
      qb1 = *(const uint4*)(q + 8);
    }
    #pragma unroll
    for (int kk = 0; kk < 2; ++kk) {
      const int nrow = wv * 16 + l16;
      bf16x8 bfrag = *(const bf16x8*)&Bs[nrow * 64 + (((kk * 4 + quad) ^ (nrow & 7)) << 3)];
      #pragma unroll
      for (int mt = 0; mt < 4; ++mt) {
        const int mrow = mt * 16 + l16;
        bf16x8 afrag = *(const bf16x8*)&As[mrow * 64 + (((kk * 4 + quad) ^ (mrow & 7)) << 3)];
        acc[mt] = __builtin_amdgcn_mfma_f32_16x16x32_bf16(afrag, bfrag, acc[mt], 0, 0, 0);
      }
    }
  }
  const int r = wv * 16 + l16;
  #pragma unroll
  for (int mt = 0; mt < 4; ++mt) {
    int s = stile * 64 + mt * 16 + quad * 4;
    float4 v = make_float4(acc[mt][0], acc[mt][1], acc[mt][2], acc[mt][3]);
    *(float4*)(sp + (((size_t)ks * BB + b) * R64 + r) * SS + s) = v;
  }
}

// ---- 4: softmax over s per (b,r): sum 4 K-partials, mask, bf16 attn out.
__global__ __launch_bounds__(256) void softmax_kernel(const float* __restrict__ sp,
                                                      const int* __restrict__ mask,
                                                      unsigned short* __restrict__ attn) {
  int br = blockIdx.x;            // b*64 + r
  int b = br >> 6;
  int tid = threadIdx.x;
  const int* mrow = mask + b * SS;
  const size_t kstride = (size_t)BB * R64 * SS;
  float vals[16];
  float mx = -INFINITY;
  #pragma unroll
  for (int j = 0; j < 16; ++j) {
    int s = tid + j * 256;
    size_t o = (size_t)br * SS + s;
    float v = sp[o] + sp[o + kstride] + sp[o + 2 * kstride] + sp[o + 3 * kstride];
    if (mrow[s] == 0) v = -INFINITY;
    vals[j] = v;
    mx = fmaxf(mx, v);
  }
  __shared__ float redm[4], reds[4];
  #pragma unroll
  for (int off = 32; off; off >>= 1) mx = fmaxf(mx, __shfl_down(mx, off, 64));
  if ((tid & 63) == 0) redm[tid >> 6] = mx;
  __syncthreads();
  mx = fmaxf(fmaxf(redm[0], redm[1]), fmaxf(redm[2], redm[3]));
  float sum = 0.f;
  #pragma unroll
  for (int j = 0; j < 16; ++j) { vals[j] = expf(vals[j] - mx); sum += vals[j]; }
  #pragma unroll
  for (int off = 32; off; off >>= 1) sum += __shfl_down(sum, off, 64);
  if ((tid & 63) == 0) reds[tid >> 6] = sum;
  __syncthreads();
  sum = reds[0] + reds[1] + reds[2] + reds[3];
  float inv = 1.f / sum;
  #pragma unroll
  for (int j = 0; j < 16; ++j)
    attn[(size_t)br * SS + tid + j * 256] = f2bf(vals[j] * inv);
}

// ---- 5: partial ctx cp[ss][b][r][i] = sum_{s-slice} attn[b][r][s]*hs_bf16[b][s][i]
// grid (64 itile, 4 ss, 4 b). Tile M=64(r) x N=64(i), K-slice=1024(s).
__global__ __launch_bounds__(256, 4) void ctx_mfma(const unsigned short* __restrict__ attn,
                                                   const unsigned short* __restrict__ hsbf,
                                                   float* __restrict__ cp) {
  __shared__ unsigned short As[64 * 64];  // [r][s] swizzled
  __shared__ unsigned short Bs[64 * 64];  // [i][s] swizzled (transposed hs tile)
  const int itile = blockIdx.x, ss = blockIdx.y, b = blockIdx.z;
  const int tid = threadIdx.x;
  const int wv = tid >> 6, lane = tid & 63;
  const int quad = lane >> 4, l16 = lane & 15;
  // A staging: thread -> (r row 0..63, 16 contiguous s); chunks 2*(tid&3), +1
  const int arow = tid >> 2, asc = (tid & 3) << 4;
  const int ch0 = (tid & 3) << 1, swa = arow & 7;
  const unsigned short* ap = attn + (size_t)(b * R64 + arow) * SS + ss * 1024 + asc;
  unsigned short* asw0 = &As[arow * 64 + (((ch0 + 0) ^ swa) << 3)];
  unsigned short* asw1 = &As[arow * 64 + (((ch0 + 1) ^ swa) << 3)];
  // B staging: thread -> s-pair p (rows 2p,2p+1), i-group g (8 cols at g*8)
  const int p = tid & 31, g = tid >> 5;
  const unsigned short* bp0 = hsbf + (size_t)(b * SS + ss * 1024 + 2 * p) * HID + itile * 64 + g * 8;
  const unsigned short* bp1 = bp0 + HID;

  f32x4 acc[4] = {};
  uint4 aa0 = *(const uint4*)(ap);
  uint4 aa1 = *(const uint4*)(ap + 8);
  uint4 hb0 = *(const uint4*)(bp0);
  uint4 hb1 = *(const uint4*)(bp1);

  for (int c = 0; c < 16; ++c) {
    __syncthreads();
    *(uint4*)asw0 = aa0;
    *(uint4*)asw1 = aa1;
    {
      unsigned int lo[4] = {hb0.x, hb0.y, hb0.z, hb0.w};
      unsigned int hi[4] = {hb1.x, hb1.y, hb1.z, hb1.w};
      #pragma unroll
      for (int t = 0; t < 4; ++t) {
        unsigned int d0 = (lo[t] & 0xffffu) | (hi[t] << 16);
        unsigned int d1 = (lo[t] >> 16) | (hi[t] & 0xffff0000u);
        int i0 = g * 8 + 2 * t, i1 = i0 + 1;
        ((unsigned int*)Bs)[i0 * 32 + (((p >> 2) ^ (i0 & 7)) << 2) + (p & 3)] = d0;
        ((unsigned int*)Bs)[i1 * 32 + (((p >> 2) ^ (i1 & 7)) << 2) + (p & 3)] = d1;
      }
    }
    __syncthreads();
    if (c < 15) {
      const unsigned short* an = ap + (size_t)(c + 1) * 64;
      aa0 = *(const uint4*)(an);
      aa1 = *(const uint4*)(an + 8);
      const unsigned short* bn0 = bp0 + (size_t)(c + 1) * 64 * HID;
      hb0 = *(const uint4*)(bn0);
      hb1 = *(const uint4*)(bn0 + HID);
    }
    #pragma unroll
    for (int kk = 0; kk < 2; ++kk) {
      const int nrow = wv * 16 + l16;
      bf16x8 bfrag = *(const bf16x8*)&Bs[nrow * 64 + (((kk * 4 + quad) ^ (nrow & 7)) << 3)];
      #pragma unroll
      for (int mt = 0; mt < 4; ++mt) {
        const int mrow = mt * 16 + l16;
        bf16x8 afrag = *(const bf16x8*)&As[mrow * 64 + (((kk * 4 + quad) ^ (mrow & 7)) << 3)];
        acc[mt] = __builtin_amdgcn_mfma_f32_16x16x32_bf16(afrag, bfrag, acc[mt], 0, 0, 0);
      }
    }
  }
  const int i = itile * 64 + wv * 16 + l16;
  #pragma unroll
  for (int mt = 0; mt < 4; ++mt) {
    int r0 = mt * 16 + quad * 4;
    #pragma unroll
    for (int j = 0; j < 4; ++j)
      cp[(((size_t)ss * BB + b) * R64 + r0 + j) * HID + i] = acc[mt][j];
  }
}

// ---- 6: out[b][n][h*64+d] = sum_i (sum_ss cp[ss][b][h*8+n][i]) * Wv[h*64+d][i]
__global__ void out_kernel(const float* __restrict__ cp, const float* __restrict__ Wv,
                           float* __restrict__ out) {
  int w = (blockIdx.x * blockDim.x + threadIdx.x) >> 6;
  int lane = threadIdx.x & 63;
  if (w >= BB * SLOTS * BD) return;   // 16384
  int b = w >> 12, n = (w >> 9) & 7, hd = w & 511, h = hd >> 6;
  const size_t sstride = (size_t)BB * R64 * HID;
  const float* c  = cp + ((size_t)b * R64 + h * 8 + n) * HID;
  const float* wv = Wv + (size_t)hd * HID;
  float acc = 0.f;
  for (int i = lane; i < HID; i += 64) {
    float s = c[i] + c[i + sstride] + c[i + 2 * sstride] + c[i + 3 * sstride];
    acc = fmaf(s, wv[i], acc);
  }
  #pragma unroll
  for (int off = 32; off; off >>= 1) acc += __shfl_down(acc, off, 64);
  if (lane == 0) out[w] = acc;
}

// ---- 7: y[b][n][o] = sum_d out[b][n][d] * Wo[o][d]
__global__ void final_kernel(const float* __restrict__ out, const float* __restrict__ Wo,
                             float* __restrict__ y) {
  int w = (blockIdx.x * blockDim.x + threadIdx.x) >> 6;
  int lane = threadIdx.x & 63;
  if (w >= BB * SLOTS * HID) return;  // 131072
  int bn = w >> 12, o = w & 4095;
  const float* orow = out + bn * BD;
  const float* wo = Wo + (size_t)o * BD;
  float acc = 0.f;
  #pragma unroll
  for (int d = lane; d < BD; d += 64) acc = fmaf(orow[d], wo[d], acc);
  #pragma unroll
  for (int off = 32; off; off >>= 1) acc += __shfl_down(acc, off, 64);
  if (lane == 0) y[w] = acc;
}

extern "C" void kernel_launch(void* const* d_in, const int* in_sizes, int n_in,
                              void* d_out, int out_size, void* d_ws, size_t ws_size,
                              hipStream_t stream) {
  const float* hs   = (const float*)d_in[0];
  const int*   mask = (const int*)d_in[1];
  const float* ms   = (const float*)d_in[2];
  const float* Wq   = (const float*)d_in[3];
  const float* Wk   = (const float*)d_in[4];
  const float* Wv   = (const float*)d_in[5];
  const float* Wo   = (const float*)d_in[6];

  // Workspace layout (~163 MB)
  char* ws = (char*)d_ws;
  float*          Q    = (float*)ws;          ws += 4096 * 4;                        // 16 KB
  unsigned short* QW   = (unsigned short*)ws; ws += (size_t)R64 * HID * 2;           // 512 KB
  float*          sp   = (float*)ws;          ws += (size_t)4 * BB * R64 * SS * 4;   // 16 MB
  unsigned short* attn = (unsigned short*)ws; ws += (size_t)BB * R64 * SS * 2;       // 2 MB
  float*          cp   = (float*)ws;          ws += (size_t)4 * BB * R64 * HID * 4;  // 16 MB
  unsigned short* hsbf = (unsigned short*)ws; ws += (size_t)BB * SS * HID * 2;       // 128 MB
  float*          out  = (float*)ws;                                                 // 64 KB

  q_kernel<<<dim3((SLOTS * BD * 64) / 256), 256, 0, stream>>>(ms, Wq, Q);
  qw_kernel<<<dim3((R64 * HID) / 256), 256, 0, stream>>>(Q, Wk, QW);
  scores_mfma<<<dim3(64, 4, 4), 256, 0, stream>>>(hs, QW, sp, hsbf);
  softmax_kernel<<<dim3(BB * R64), 256, 0, stream>>>(sp, mask, attn);
  ctx_mfma<<<dim3(64, 4, 4), 256, 0, stream>>>(attn, hsbf, cp);
  out_kernel<<<dim3(4096), 256, 0, stream>>>(cp, Wv, out);
  final_kernel<<<dim3(32768), 256, 0, stream>>>(out, Wo, (float*)d_out);
}